// Round 2
// 534.546 us; speedup vs baseline: 1.1843x; 1.1843x over previous
//
#include <hip/hip_runtime.h>
#include <hip/hip_bf16.h>

typedef unsigned short u16;
typedef unsigned int   u32;

// bf16 (stored as u16) <-> f32. Decode exact; encode round-to-nearest-even.
__device__ __forceinline__ float b2f(u16 v){ return __uint_as_float(((u32)v) << 16); }
__device__ __forceinline__ u16   f2b(float f){
  u32 u = __float_as_uint(f);
  u += 0x7fffu + ((u >> 16) & 1u);
  return (u16)(u >> 16);
}
__device__ __forceinline__ float gelu_exact(float x){
  return 0.5f * x * (1.0f + erff(x * 0.70710678118654752440f));
}

// ---------------------------------------------------------------------------
// K1 (fc1a) v2: p-outer accumulator structure.
// out1[row][f], f=k*27+j = sum_{p<53} xe[row][k*53+p]*w1[k][j][p]
// act column-major bf16: act[f*Bc + row]. Grid (Bc/256, 15), block 256.
// Changes vs v1 (326us, occ 21.6%, VALUBusy 25.6%):
//  - 256 rows/block, 1 row/thread, acc[28] in VGPRs (fits; v1's xb[112] did
//    not and was rematerialized as ~3000 ds_read_u16/thread).
//  - x streamed as paired-bf16 dwords (27 ds_read_b32/thread total).
//  - weights transposed wt[p][j], read wave-uniform as float4 (broadcast).
//  - LDS 33.7 KB -> 4 blocks/CU (16 waves/CU, 2x v1 occupancy).
// ---------------------------------------------------------------------------
__global__ __launch_bounds__(256, 4) void k_fc1a(
    const float* __restrict__ x, const float* __restrict__ w1,
    u16* __restrict__ act, int base, int Bc)
{
  __shared__ __align__(16) float wt[54*28];   // wt[p*28+j], zero-padded
  __shared__ __align__(4)  u16  xs[256*54];   // row stride 54 elems (odd*27 banks)
  const int tid = threadIdx.x;
  const int k   = blockIdx.y;
  const int rowloc = blockIdx.x * 256;

  // stage weights transposed + zero-padded: w1[(k*27+j)*53+p] -> wt[p][j]
  for (int e = tid; e < 54*28; e += 256){
    int p = e / 28, j = e - p*28;
    wt[e] = (p < 53 && j < 27) ? w1[(k*27 + j)*53 + p] : 0.0f;
  }
  // stage x tile: 256 rows x 53 cols (bf16), elem 53 zero pad, coalesced-ish
  #pragma unroll 4
  for (int i = 0; i < 54; ++i){
    int e = i*256 + tid;
    int r = e / 54, c = e - r*54;
    int col = k*53 + c;
    float v = 0.0f;
    if (c < 53 && col < 784) v = x[(size_t)(base + rowloc + r)*784 + col];
    xs[e] = f2b(v);
  }
  __syncthreads();

  float acc[28];
  #pragma unroll
  for (int j = 0; j < 28; ++j) acc[j] = 0.0f;

  // xs row is 4B-aligned (54*2B = 108B stride); read bf16 pairs as dwords.
  const u32* xrow = (const u32*)&xs[tid*54];
  #pragma unroll 3
  for (int pp = 0; pp < 27; ++pp){
    const u32 xv2 = xrow[pp];
    const float x0 = __uint_as_float(xv2 << 16);         // p = 2pp   (low u16)
    const float x1 = __uint_as_float(xv2 & 0xffff0000u); // p = 2pp+1 (high u16)
    const float4* wa = (const float4*)&wt[(2*pp  )*28];
    const float4* wb = (const float4*)&wt[(2*pp+1)*28];
    #pragma unroll
    for (int i = 0; i < 7; ++i){
      const float4 a = wa[i];
      const float4 b = wb[i];
      acc[4*i+0] = fmaf(a.x, x0, fmaf(b.x, x1, acc[4*i+0]));
      acc[4*i+1] = fmaf(a.y, x0, fmaf(b.y, x1, acc[4*i+1]));
      acc[4*i+2] = fmaf(a.z, x0, fmaf(b.z, x1, acc[4*i+2]));
      acc[4*i+3] = fmaf(a.w, x0, fmaf(b.w, x1, acc[4*i+3]));
    }
  }
  const int r0 = rowloc + tid;
  #pragma unroll
  for (int j = 0; j < 27; ++j)
    act[(size_t)(k*27 + j)*Bc + r0] = f2b(acc[j]);
}

// ---------------------------------------------------------------------------
// K2 (fc1b): split over l. Grid (Bc/256, 15), block 256, one row x one l per
// thread. h1[m], m=s*15+l = gelu(sum_r out1[r*15+l]*w2[l][s][r] + b1[m]) for
// m<392 else 0.  In-place on act: block (rowtile,l) reads cols {r*15+l} and
// writes cols {s*15+l} for ITS OWN rows only -> no cross-block hazard.
// ---------------------------------------------------------------------------
__global__ __launch_bounds__(256) void k_fc1b(
    const float* __restrict__ w2, const float* __restrict__ b1,
    u16* act, int Bc)
{
  __shared__ __align__(16) float w2s[27*28];
  __shared__ float b1s[27];
  const int tid = threadIdx.x;
  const int l   = blockIdx.y;
  for (int e = tid; e < 27*28; e += 256){
    int s = e / 28, r = e - s*28;
    w2s[e] = (r < 27) ? w2[(l*27 + s)*27 + r] : 0.0f;
  }
  if (tid < 27){
    int m = tid*15 + l;
    b1s[tid] = (m < 392) ? b1[m] : 0.0f;
  }
  __syncthreads();

  const int row = blockIdx.x*256 + tid;
  float t[28];
  #pragma unroll
  for (int r = 0; r < 27; ++r) t[r] = b2f(act[(size_t)(r*15 + l)*Bc + row]);
  t[27] = 0.0f;
  #pragma unroll
  for (int s = 0; s < 27; ++s){
    const float* wp = &w2s[s*28];
    float va = 0.f, vb = 0.f;
    #pragma unroll
    for (int i = 0; i < 7; ++i){
      const float4 w = *(const float4*)&wp[4*i];
      va = fmaf(w.x, t[4*i+0], va); vb = fmaf(w.y, t[4*i+1], vb);
      va = fmaf(w.z, t[4*i+2], va); vb = fmaf(w.w, t[4*i+3], vb);
    }
    const int m = s*15 + l;
    float h = (m < 392) ? gelu_exact(va + vb + b1s[s]) : 0.0f;
    act[(size_t)m*Bc + row] = f2b(h);
  }
}

// ---------------------------------------------------------------------------
// K3 (fc2a): split over k. Grid (Bc/256, 15). o2[k*9+j] =
// sum_{p<27} h1[k*27+p]*w1_2[k][j][p]; write o2t column-major bf16.
// ---------------------------------------------------------------------------
__global__ __launch_bounds__(256) void k_fc2a(
    const u16* __restrict__ h1t, const float* __restrict__ w1_2,
    u16* __restrict__ o2t, int Bc)
{
  __shared__ __align__(16) float ws[9*28];
  const int tid = threadIdx.x;
  const int k   = blockIdx.y;
  for (int e = tid; e < 9*28; e += 256){
    int j = e / 28, p = e - j*28;
    ws[e] = (p < 27) ? w1_2[(k*9 + j)*27 + p] : 0.0f;
  }
  __syncthreads();

  const int row = blockIdx.x*256 + tid;
  float hb[28];
  #pragma unroll
  for (int p = 0; p < 27; ++p) hb[p] = b2f(h1t[(size_t)(k*27 + p)*Bc + row]);
  hb[27] = 0.0f;
  #pragma unroll
  for (int j = 0; j < 9; ++j){
    const float* wp = &ws[j*28];
    float va = 0.f, vb = 0.f;
    #pragma unroll
    for (int i = 0; i < 7; ++i){
      const float4 w = *(const float4*)&wp[4*i];
      va = fmaf(w.x, hb[4*i+0], va); vb = fmaf(w.y, hb[4*i+1], vb);
      va = fmaf(w.z, hb[4*i+2], va); vb = fmaf(w.w, hb[4*i+3], vb);
    }
    o2t[(size_t)(k*9 + j)*Bc + row] = f2b(va + vb);
  }
}

// ---------------------------------------------------------------------------
// K4 (fc2b): split over l. Grid (Bc/256, 15). h2[m], m=s*15+l =
// gelu(sum_{r<9} o2[r*15+l]*w2_2[l][s][r] + b2[m]) for m<128 else 0.
// ---------------------------------------------------------------------------
__global__ __launch_bounds__(256) void k_fc2b(
    const u16* __restrict__ o2t, const float* __restrict__ w2_2,
    const float* __restrict__ b2, u16* __restrict__ h2t, int Bc)
{
  __shared__ float ws[9*9];
  __shared__ float b2s[9];
  const int tid = threadIdx.x;
  const int l   = blockIdx.y;
  if (tid < 81) ws[tid] = w2_2[l*81 + tid];
  if (tid < 9){
    int m = tid*15 + l;
    b2s[tid] = (m < 128) ? b2[m] : 0.0f;
  }
  __syncthreads();

  const int row = blockIdx.x*256 + tid;
  float t[9];
  #pragma unroll
  for (int r = 0; r < 9; ++r) t[r] = b2f(o2t[(size_t)(r*15 + l)*Bc + row]);
  #pragma unroll
  for (int s = 0; s < 9; ++s){
    const float* wp = &ws[s*9];
    float v = 0.f;
    #pragma unroll
    for (int r = 0; r < 9; ++r) v = fmaf(wp[r], t[r], v);
    const int m = s*15 + l;
    float h = (m < 128) ? gelu_exact(v + b2s[s]) : 0.0f;
    h2t[(size_t)m*Bc + row] = f2b(h);
  }
}

// ---------------------------------------------------------------------------
// K5 (fc3a): split over k. Grid (Bc/256, 15). o3[k*5+j] =
// sum_{p<9} h2[k*9+p]*w1_3[k][j][p]; o3t column-major bf16.
// ---------------------------------------------------------------------------
__global__ __launch_bounds__(256) void k_fc3a(
    const u16* __restrict__ h2t, const float* __restrict__ w1_3,
    u16* __restrict__ o3t, int Bc)
{
  __shared__ float ws[5*9];
  const int tid = threadIdx.x;
  const int k   = blockIdx.y;
  if (tid < 45) ws[tid] = w1_3[k*45 + tid];
  __syncthreads();

  const int row = blockIdx.x*256 + tid;
  float hb[9];
  #pragma unroll
  for (int p = 0; p < 9; ++p) hb[p] = b2f(h2t[(size_t)(k*9 + p)*Bc + row]);
  #pragma unroll
  for (int j = 0; j < 5; ++j){
    const float* wp = &ws[j*9];
    float v = 0.f;
    #pragma unroll
    for (int p = 0; p < 9; ++p) v = fmaf(wp[p], hb[p], v);
    o3t[(size_t)(k*5 + j)*Bc + row] = f2b(v);
  }
}

// ---------------------------------------------------------------------------
// K6 (fc3b + fc4 + log_softmax): one row/thread, grid Bc/256.
// h3[m]=gelu(sum_r o3[r*15+l]*w2_3[l][s][r]+b3[m]) (m=s*15+l<50) folded
// immediately into fc4 accumulators sacc[c] (c=m/5, static) -> never >40 live.
// Output staged through LDS for coalesced f32 stores.
// ---------------------------------------------------------------------------
__global__ __launch_bounds__(256) void k_fc3b4(
    const u16* __restrict__ o3t,
    const float* __restrict__ w2_3, const float* __restrict__ b3,
    const float* __restrict__ w1_4, const float* __restrict__ w2_4, const float* __restrict__ b4,
    float* __restrict__ out, int base, int Bc)
{
  __shared__ __align__(16) float w23s[75*8];
  __shared__ float b3s[64];
  __shared__ float w14s[10*8];
  __shared__ float w24s[10];
  __shared__ float b4s[10];
  __shared__ float outS[256*10];
  const int tid = threadIdx.x;
  for (int e = tid; e < 75*8; e += 256){ int a=e/8, r=e-a*8; w23s[e] = (r<5)? w2_3[a*5+r] : 0.f; }
  for (int e = tid; e < 64;   e += 256) b3s[e] = b3[e];
  for (int e = tid; e < 80;   e += 256){ int c=e/8, p=e-c*8; w14s[e] = (p<5)? w1_4[c*5+p] : 0.f; }
  if (tid < 10){ w24s[tid] = w2_4[tid]; b4s[tid] = b4[tid]; }
  __syncthreads();

  const int rloc = blockIdx.x*256 + tid;

  float sacc[10];
  #pragma unroll
  for (int c = 0; c < 10; ++c) sacc[c] = 0.0f;

  #pragma unroll
  for (int l = 0; l < 15; ++l){
    float t[5];
    #pragma unroll
    for (int r = 0; r < 5; ++r) t[r] = b2f(o3t[(size_t)(r*15 + l)*Bc + rloc]);
    #pragma unroll
    for (int s = 0; s < 5; ++s){
      const int m = s*15 + l;
      if (m < 50){
        const float* wp = &w23s[(l*5 + s)*8];
        float v = 0.f;
        v = fmaf(wp[0], t[0], v); v = fmaf(wp[1], t[1], v);
        v = fmaf(wp[2], t[2], v); v = fmaf(wp[3], t[3], v);
        v = fmaf(wp[4], t[4], v);
        const float h = gelu_exact(v + b3s[m]);
        const int c = m / 5, p = m - (m/5)*5;      // compile-time constants
        sacc[c] = fmaf(h, w14s[c*8 + p], sacc[c]);
      }
    }
  }
  float v[10];
  #pragma unroll
  for (int c = 0; c < 10; ++c) v[c] = fmaf(sacc[c], w24s[c], b4s[c]);

  float mx = v[0];
  #pragma unroll
  for (int c = 1; c < 10; ++c) mx = fmaxf(mx, v[c]);
  float sum = 0.f;
  #pragma unroll
  for (int c = 0; c < 10; ++c) sum += expf(v[c] - mx);
  const float lse = mx + logf(sum);
  #pragma unroll
  for (int c = 0; c < 10; ++c) outS[tid*10 + c] = v[c] - lse;
  __syncthreads();
  const size_t blockOut = (size_t)(base + blockIdx.x*256) * 10;
  #pragma unroll
  for (int i = 0; i < 10; ++i){
    int e = i*256 + tid;
    out[blockOut + e] = outS[e];
  }
}

// ---------------------------------------------------------------------------
extern "C" void kernel_launch(void* const* d_in, const int* in_sizes, int n_in,
                              void* d_out, int out_size, void* d_ws, size_t ws_size,
                              hipStream_t stream)
{
  const float* x     = (const float*)d_in[0];
  const float* f1w1  = (const float*)d_in[1];
  const float* f1w2  = (const float*)d_in[2];
  const float* f1b   = (const float*)d_in[3];
  const float* f2w1  = (const float*)d_in[4];
  const float* f2w2  = (const float*)d_in[5];
  const float* f2b   = (const float*)d_in[6];
  const float* f3w1  = (const float*)d_in[7];
  const float* f3w2  = (const float*)d_in[8];
  const float* f3b   = (const float*)d_in[9];
  const float* f4w1  = (const float*)d_in[10];
  const float* f4w2  = (const float*)d_in[11];
  const float* f4b   = (const float*)d_in[12];
  const int B = in_sizes[0] / 784;           // 65536
  (void)n_in; (void)out_size;

  // ws per chunk of Bc rows (column-major bf16 streams):
  //   act 405 | o2t 135 | h2t 135 | o3t 75  = 750 u16 per row (1500 B)
  const size_t perRow = 750 * sizeof(u16);
  int Rc = B;
  if (ws_size < (size_t)B * perRow){
    size_t rows = ws_size / perRow;
    Rc = (int)(rows & ~(size_t)511);
    if (Rc < 512) Rc = 512;
  }
  for (int base = 0; base < B; base += Rc){
    const int Bc = (B - base < Rc) ? (B - base) : Rc;
    u16* act = (u16*)d_ws;
    u16* o2t = act + (size_t)405 * Bc;
    u16* h2t = o2t + (size_t)135 * Bc;
    u16* o3t = h2t + (size_t)135 * Bc;
    k_fc1a<<<dim3(Bc/256, 15), 256, 0, stream>>>(x, f1w1, act, base, Bc);
    k_fc1b<<<dim3(Bc/256, 15), 256, 0, stream>>>(f1w2, f1b, act, Bc);
    k_fc2a<<<dim3(Bc/256, 15), 256, 0, stream>>>(act, f2w1, o2t, Bc);
    k_fc2b<<<dim3(Bc/256, 15), 256, 0, stream>>>(o2t, f2w2, f2b, h2t, Bc);
    k_fc3a<<<dim3(Bc/256, 15), 256, 0, stream>>>(h2t, f3w1, o3t, Bc);
    k_fc3b4<<<dim3(Bc/256), 256, 0, stream>>>(o3t, f3w2, f3b,
                                              f4w1, f4w2, f4b, (float*)d_out, base, Bc);
  }
}

// Round 3
// 457.038 us; speedup vs baseline: 1.3851x; 1.1696x over previous
//
#include <hip/hip_runtime.h>
#include <hip/hip_bf16.h>

typedef unsigned short u16;
typedef unsigned int   u32;

// bf16 (stored as u16) <-> f32. Decode exact; encode round-to-nearest-even.
__device__ __forceinline__ float b2f(u16 v){ return __uint_as_float(((u32)v) << 16); }
__device__ __forceinline__ u16   f2b(float f){
  u32 u = __float_as_uint(f);
  u += 0x7fffu + ((u >> 16) & 1u);
  return (u16)(u >> 16);
}
__device__ __forceinline__ float gelu_exact(float x){
  return 0.5f * x * (1.0f + erff(x * 0.70710678118654752440f));
}

// ---------------------------------------------------------------------------
// K0 (prep): transpose+pad fc1 w1 into workspace: wtg[k][p][j], p<54, j<28
// (rows of 28 floats = 112 B, 16B-aligned). Runs once; ~23k elements.
// ---------------------------------------------------------------------------
__global__ __launch_bounds__(256) void k_prep_w1(
    const float* __restrict__ w1, float* __restrict__ wtg)
{
  int tid = blockIdx.x*256 + threadIdx.x;
  for (int e = tid; e < 15*54*28; e += gridDim.x*256){
    int kk = e / 1512, rem = e - kk*1512;
    int p = rem / 28, j = rem - p*28;
    wtg[e] = (p < 53 && j < 27) ? w1[(kk*27 + j)*53 + p] : 0.0f;
  }
}

// ---------------------------------------------------------------------------
// K1 (fc1a) v3: weights via wave-uniform GLOBAL reads (s_load -> SGPR),
// x tile in LDS as packed bf16 pairs.
// v2 post-mortem: 378 broadcast ds_read_b128/thread made fc1a LDS-pipe-bound
// (~122us floor per-CU); VALUBusy 26%, occ 43%, dur 228us.
// v3: LDS = x only (27.6 KB -> 5 blocks/CU); weight FMA operand comes from
// SGPRs (uniform index, 1 sgpr/VALU-inst legal); full pp-unroll lets LLVM
// batch s_loads ahead of the FMAs. VALU floor ~24us/CU.
// out1[row][f], f=k*27+j = sum_{p<53} xe[row][k*53+p]*w1[k][j][p]
// act column-major bf16: act[f*Bc + row]. Grid (Bc/256, 15), block 256.
// ---------------------------------------------------------------------------
__global__ __launch_bounds__(256, 5) void k_fc1a(
    const float* __restrict__ x, const float* __restrict__ wtg,
    u16* __restrict__ act, int base, int Bc)
{
  __shared__ u32 xsu[256*27];     // row stride 27 u32 (odd -> conflict-free)
  const int tid = threadIdx.x;
  const int k   = blockIdx.y;
  const int rowloc = blockIdx.x * 256;

  // stage x tile: 256 rows x 53 cols as 27 packed-bf16 dwords per row
  #pragma unroll 4
  for (int i = 0; i < 27; ++i){
    int e = i*256 + tid;                 // < 6912
    int r = e / 27, c2 = e - r*27;
    int col = k*53 + 2*c2;               // 2*c2 <= 52 < 53 always
    const size_t rowoff = (size_t)(base + rowloc + r)*784;
    float v0 = 0.f, v1 = 0.f;
    if (col < 784) v0 = x[rowoff + col];
    if (2*c2+1 < 53 && col+1 < 784) v1 = x[rowoff + col + 1];
    xsu[e] = (u32)f2b(v0) | ((u32)f2b(v1) << 16);
  }
  __syncthreads();

  float acc[28];
  #pragma unroll
  for (int j = 0; j < 28; ++j) acc[j] = 0.0f;

  const float* __restrict__ wk = wtg + (size_t)k*1512;   // 54*28
  const u32* xrow = &xsu[tid*27];
  #pragma unroll
  for (int pp = 0; pp < 27; ++pp){
    const u32 xv2 = xrow[pp];
    const float x0 = __uint_as_float(xv2 << 16);          // p = 2pp
    const float x1 = __uint_as_float(xv2 & 0xffff0000u);  // p = 2pp+1
    const float4* wa = (const float4*)(wk + 56*pp);       // row 2pp   (28 f)
    const float4* wb = (const float4*)(wk + 56*pp + 28);  // row 2pp+1 (28 f)
    #pragma unroll
    for (int i = 0; i < 7; ++i){
      const float4 a = wa[i];
      const float4 b = wb[i];
      acc[4*i+0] = fmaf(a.x, x0, fmaf(b.x, x1, acc[4*i+0]));
      acc[4*i+1] = fmaf(a.y, x0, fmaf(b.y, x1, acc[4*i+1]));
      acc[4*i+2] = fmaf(a.z, x0, fmaf(b.z, x1, acc[4*i+2]));
      acc[4*i+3] = fmaf(a.w, x0, fmaf(b.w, x1, acc[4*i+3]));
    }
  }
  const int r0 = rowloc + tid;
  #pragma unroll
  for (int j = 0; j < 27; ++j)
    act[(size_t)(k*27 + j)*Bc + r0] = f2b(acc[j]);
}

// ---------------------------------------------------------------------------
// K2 (fc1b): split over l. Grid (Bc/256, 15), block 256, one row x one l per
// thread. h1[m], m=s*15+l = gelu(sum_r out1[r*15+l]*w2[l][s][r] + b1[m]) for
// m<392 else 0.  In-place on act: block (rowtile,l) reads cols {r*15+l} and
// writes cols {s*15+l} for ITS OWN rows only -> no cross-block hazard.
// ---------------------------------------------------------------------------
__global__ __launch_bounds__(256) void k_fc1b(
    const float* __restrict__ w2, const float* __restrict__ b1,
    u16* act, int Bc)
{
  __shared__ __align__(16) float w2s[27*28];
  __shared__ float b1s[27];
  const int tid = threadIdx.x;
  const int l   = blockIdx.y;
  for (int e = tid; e < 27*28; e += 256){
    int s = e / 28, r = e - s*28;
    w2s[e] = (r < 27) ? w2[(l*27 + s)*27 + r] : 0.0f;
  }
  if (tid < 27){
    int m = tid*15 + l;
    b1s[tid] = (m < 392) ? b1[m] : 0.0f;
  }
  __syncthreads();

  const int row = blockIdx.x*256 + tid;
  float t[28];
  #pragma unroll
  for (int r = 0; r < 27; ++r) t[r] = b2f(act[(size_t)(r*15 + l)*Bc + row]);
  t[27] = 0.0f;
  #pragma unroll
  for (int s = 0; s < 27; ++s){
    const float* wp = &w2s[s*28];
    float va = 0.f, vb = 0.f;
    #pragma unroll
    for (int i = 0; i < 7; ++i){
      const float4 w = *(const float4*)&wp[4*i];
      va = fmaf(w.x, t[4*i+0], va); vb = fmaf(w.y, t[4*i+1], vb);
      va = fmaf(w.z, t[4*i+2], va); vb = fmaf(w.w, t[4*i+3], vb);
    }
    const int m = s*15 + l;
    float h = (m < 392) ? gelu_exact(va + vb + b1s[s]) : 0.0f;
    act[(size_t)m*Bc + row] = f2b(h);
  }
}

// ---------------------------------------------------------------------------
// K3 (fc2a): split over k. Grid (Bc/256, 15). o2[k*9+j] =
// sum_{p<27} h1[k*27+p]*w1_2[k][j][p]; write o2t column-major bf16.
// ---------------------------------------------------------------------------
__global__ __launch_bounds__(256) void k_fc2a(
    const u16* __restrict__ h1t, const float* __restrict__ w1_2,
    u16* __restrict__ o2t, int Bc)
{
  __shared__ __align__(16) float ws[9*28];
  const int tid = threadIdx.x;
  const int k   = blockIdx.y;
  for (int e = tid; e < 9*28; e += 256){
    int j = e / 28, p = e - j*28;
    ws[e] = (p < 27) ? w1_2[(k*9 + j)*27 + p] : 0.0f;
  }
  __syncthreads();

  const int row = blockIdx.x*256 + tid;
  float hb[28];
  #pragma unroll
  for (int p = 0; p < 27; ++p) hb[p] = b2f(h1t[(size_t)(k*27 + p)*Bc + row]);
  hb[27] = 0.0f;
  #pragma unroll
  for (int j = 0; j < 9; ++j){
    const float* wp = &ws[j*28];
    float va = 0.f, vb = 0.f;
    #pragma unroll
    for (int i = 0; i < 7; ++i){
      const float4 w = *(const float4*)&wp[4*i];
      va = fmaf(w.x, hb[4*i+0], va); vb = fmaf(w.y, hb[4*i+1], vb);
      va = fmaf(w.z, hb[4*i+2], va); vb = fmaf(w.w, hb[4*i+3], vb);
    }
    o2t[(size_t)(k*9 + j)*Bc + row] = f2b(va + vb);
  }
}

// ---------------------------------------------------------------------------
// K4 (fc2b): split over l. Grid (Bc/256, 15). h2[m], m=s*15+l =
// gelu(sum_{r<9} o2[r*15+l]*w2_2[l][s][r] + b2[m]) for m<128 else 0.
// ---------------------------------------------------------------------------
__global__ __launch_bounds__(256) void k_fc2b(
    const u16* __restrict__ o2t, const float* __restrict__ w2_2,
    const float* __restrict__ b2, u16* __restrict__ h2t, int Bc)
{
  __shared__ float ws[9*9];
  __shared__ float b2s[9];
  const int tid = threadIdx.x;
  const int l   = blockIdx.y;
  if (tid < 81) ws[tid] = w2_2[l*81 + tid];
  if (tid < 9){
    int m = tid*15 + l;
    b2s[tid] = (m < 128) ? b2[m] : 0.0f;
  }
  __syncthreads();

  const int row = blockIdx.x*256 + tid;
  float t[9];
  #pragma unroll
  for (int r = 0; r < 9; ++r) t[r] = b2f(o2t[(size_t)(r*15 + l)*Bc + row]);
  #pragma unroll
  for (int s = 0; s < 9; ++s){
    const float* wp = &ws[s*9];
    float v = 0.f;
    #pragma unroll
    for (int r = 0; r < 9; ++r) v = fmaf(wp[r], t[r], v);
    const int m = s*15 + l;
    float h = (m < 128) ? gelu_exact(v + b2s[s]) : 0.0f;
    h2t[(size_t)m*Bc + row] = f2b(h);
  }
}

// ---------------------------------------------------------------------------
// K5 (fc3a): split over k. Grid (Bc/256, 15). o3[k*5+j] =
// sum_{p<9} h2[k*9+p]*w1_3[k][j][p]; o3t column-major bf16.
// ---------------------------------------------------------------------------
__global__ __launch_bounds__(256) void k_fc3a(
    const u16* __restrict__ h2t, const float* __restrict__ w1_3,
    u16* __restrict__ o3t, int Bc)
{
  __shared__ float ws[5*9];
  const int tid = threadIdx.x;
  const int k   = blockIdx.y;
  if (tid < 45) ws[tid] = w1_3[k*45 + tid];
  __syncthreads();

  const int row = blockIdx.x*256 + tid;
  float hb[9];
  #pragma unroll
  for (int p = 0; p < 9; ++p) hb[p] = b2f(h2t[(size_t)(k*9 + p)*Bc + row]);
  #pragma unroll
  for (int j = 0; j < 5; ++j){
    const float* wp = &ws[j*9];
    float v = 0.f;
    #pragma unroll
    for (int p = 0; p < 9; ++p) v = fmaf(wp[p], hb[p], v);
    o3t[(size_t)(k*5 + j)*Bc + row] = f2b(v);
  }
}

// ---------------------------------------------------------------------------
// K6 (fc3b + fc4 + log_softmax): one row/thread, grid Bc/256.
// h3[m]=gelu(sum_r o3[r*15+l]*w2_3[l][s][r]+b3[m]) (m=s*15+l<50) folded
// immediately into fc4 accumulators sacc[c] (c=m/5, static) -> never >40 live.
// Output staged through LDS for coalesced f32 stores.
// ---------------------------------------------------------------------------
__global__ __launch_bounds__(256) void k_fc3b4(
    const u16* __restrict__ o3t,
    const float* __restrict__ w2_3, const float* __restrict__ b3,
    const float* __restrict__ w1_4, const float* __restrict__ w2_4, const float* __restrict__ b4,
    float* __restrict__ out, int base, int Bc)
{
  __shared__ __align__(16) float w23s[75*8];
  __shared__ float b3s[64];
  __shared__ float w14s[10*8];
  __shared__ float w24s[10];
  __shared__ float b4s[10];
  __shared__ float outS[256*10];
  const int tid = threadIdx.x;
  for (int e = tid; e < 75*8; e += 256){ int a=e/8, r=e-a*8; w23s[e] = (r<5)? w2_3[a*5+r] : 0.f; }
  for (int e = tid; e < 64;   e += 256) b3s[e] = b3[e];
  for (int e = tid; e < 80;   e += 256){ int c=e/8, p=e-c*8; w14s[e] = (p<5)? w1_4[c*5+p] : 0.f; }
  if (tid < 10){ w24s[tid] = w2_4[tid]; b4s[tid] = b4[tid]; }
  __syncthreads();

  const int rloc = blockIdx.x*256 + tid;

  float sacc[10];
  #pragma unroll
  for (int c = 0; c < 10; ++c) sacc[c] = 0.0f;

  #pragma unroll
  for (int l = 0; l < 15; ++l){
    float t[5];
    #pragma unroll
    for (int r = 0; r < 5; ++r) t[r] = b2f(o3t[(size_t)(r*15 + l)*Bc + rloc]);
    #pragma unroll
    for (int s = 0; s < 5; ++s){
      const int m = s*15 + l;
      if (m < 50){
        const float* wp = &w23s[(l*5 + s)*8];
        float v = 0.f;
        v = fmaf(wp[0], t[0], v); v = fmaf(wp[1], t[1], v);
        v = fmaf(wp[2], t[2], v); v = fmaf(wp[3], t[3], v);
        v = fmaf(wp[4], t[4], v);
        const float h = gelu_exact(v + b3s[m]);
        const int c = m / 5, p = m - (m/5)*5;      // compile-time constants
        sacc[c] = fmaf(h, w14s[c*8 + p], sacc[c]);
      }
    }
  }
  float v[10];
  #pragma unroll
  for (int c = 0; c < 10; ++c) v[c] = fmaf(sacc[c], w24s[c], b4s[c]);

  float mx = v[0];
  #pragma unroll
  for (int c = 1; c < 10; ++c) mx = fmaxf(mx, v[c]);
  float sum = 0.f;
  #pragma unroll
  for (int c = 0; c < 10; ++c) sum += expf(v[c] - mx);
  const float lse = mx + logf(sum);
  #pragma unroll
  for (int c = 0; c < 10; ++c) outS[tid*10 + c] = v[c] - lse;
  __syncthreads();
  const size_t blockOut = (size_t)(base + blockIdx.x*256) * 10;
  #pragma unroll
  for (int i = 0; i < 10; ++i){
    int e = i*256 + tid;
    out[blockOut + e] = outS[e];
  }
}

// ---------------------------------------------------------------------------
extern "C" void kernel_launch(void* const* d_in, const int* in_sizes, int n_in,
                              void* d_out, int out_size, void* d_ws, size_t ws_size,
                              hipStream_t stream)
{
  const float* x     = (const float*)d_in[0];
  const float* f1w1  = (const float*)d_in[1];
  const float* f1w2  = (const float*)d_in[2];
  const float* f1b   = (const float*)d_in[3];
  const float* f2w1  = (const float*)d_in[4];
  const float* f2w2  = (const float*)d_in[5];
  const float* f2b   = (const float*)d_in[6];
  const float* f3w1  = (const float*)d_in[7];
  const float* f3w2  = (const float*)d_in[8];
  const float* f3b   = (const float*)d_in[9];
  const float* f4w1  = (const float*)d_in[10];
  const float* f4w2  = (const float*)d_in[11];
  const float* f4b   = (const float*)d_in[12];
  const int B = in_sizes[0] / 784;           // 65536
  (void)n_in; (void)out_size;

  // ws layout: [wtg: 15*54*28 f32 = 90720 B, padded to 90880]
  //            [act 405 | o2t 135 | h2t 135 | o3t 75 u16 per row = 1500 B/row]
  const size_t wtgBytes = 90880;
  float* wtg = (float*)d_ws;
  u16*  wsAct = (u16*)((char*)d_ws + wtgBytes);

  k_prep_w1<<<dim3(32), 256, 0, stream>>>(f1w1, wtg);

  const size_t perRow = 750 * sizeof(u16);
  int Rc = B;
  if (ws_size - wtgBytes < (size_t)B * perRow){
    size_t rows = (ws_size - wtgBytes) / perRow;
    Rc = (int)(rows & ~(size_t)511);
    if (Rc < 512) Rc = 512;
  }
  for (int base = 0; base < B; base += Rc){
    const int Bc = (B - base < Rc) ? (B - base) : Rc;
    u16* act = wsAct;
    u16* o2t = act + (size_t)405 * Bc;
    u16* h2t = o2t + (size_t)135 * Bc;
    u16* o3t = h2t + (size_t)135 * Bc;
    k_fc1a<<<dim3(Bc/256, 15), 256, 0, stream>>>(x, wtg, act, base, Bc);
    k_fc1b<<<dim3(Bc/256, 15), 256, 0, stream>>>(f1w2, f1b, act, Bc);
    k_fc2a<<<dim3(Bc/256, 15), 256, 0, stream>>>(act, f2w1, o2t, Bc);
    k_fc2b<<<dim3(Bc/256, 15), 256, 0, stream>>>(o2t, f2w2, f2b, h2t, Bc);
    k_fc3a<<<dim3(Bc/256, 15), 256, 0, stream>>>(h2t, f3w1, o3t, Bc);
    k_fc3b4<<<dim3(Bc/256), 256, 0, stream>>>(o3t, f3w2, f3b,
                                              f4w1, f4w2, f4b, (float*)d_out, base, Bc);
  }
}